// Round 16
// baseline (265.956 us; speedup 1.0000x reference)
//
#include <hip/hip_runtime.h>
#include <cstdint>
#include <cstddef>

typedef __bf16 bf16_t;
typedef __bf16 bf16x4 __attribute__((ext_vector_type(4)));
typedef __bf16 bf16x8 __attribute__((ext_vector_type(8)));
typedef float  f32x4  __attribute__((ext_vector_type(4)));

#define LDQ 3072   // QKV buffer row stride (elements)

// ---------------- fused cast f32 -> bf16: 4 regions, one launch ----------------
__global__ __launch_bounds__(256)
void cast4_kernel(const float* __restrict__ s0, bf16_t* __restrict__ d0,  // seq   1048576
                  const float* __restrict__ s1, bf16_t* __restrict__ d1,  // Wq    524288
                  const float* __restrict__ s2, bf16_t* __restrict__ d2,  // Wkv   262144
                  const float* __restrict__ s3, bf16_t* __restrict__ d3)  // Wo    524288
{
  int i = blockIdx.x * 256 + threadIdx.x;     // 8-elem unit index, total 2359296
  const float* src; bf16_t* dst; int off;
  if (i < 1048576)      { src = s0; dst = d0; off = i; }
  else if (i < 1572864) { src = s1; dst = d1; off = i - 1048576; }
  else if (i < 1835008) { src = s2; dst = d2; off = i - 1572864; }
  else                  { src = s3; dst = d3; off = i - 1835008; }
  const float4* p = reinterpret_cast<const float4*>(src) + (size_t)off * 2;
  float4 a = p[0], b = p[1];
  bf16x8 o;
  o[0] = (bf16_t)a.x; o[1] = (bf16_t)a.y; o[2] = (bf16_t)a.z; o[3] = (bf16_t)a.w;
  o[4] = (bf16_t)b.x; o[5] = (bf16_t)b.y; o[6] = (bf16_t)b.z; o[7] = (bf16_t)b.w;
  *reinterpret_cast<bf16x8*>(dst + (size_t)off * 8) = o;
}

// ---------------- GEMM 128x128, BK=32, 4-phase counted-vmcnt (r11) ----------
template <int MODE>
__global__ __launch_bounds__(256, 3)
void gemm128(const bf16_t* __restrict__ A, const bf16_t* __restrict__ B,
             const float* __restrict__ bias0, const float* __restrict__ bias1,
             void* __restrict__ out0, float* __restrict__ kvout,
             bf16_t* __restrict__ vt, int M, int N, int K) {
  __shared__ __align__(16) char smem[32768];
  const int t = threadIdx.x;
  const int l = t & 63;
  const int lr = l & 15, lh = l >> 4;
  const int w = t >> 6;
  const int wm = w >> 1, wn = w & 1;
  const int m0 = blockIdx.x * 128, n0 = blockIdx.y * 128;

  const char* Ag = (const char*)(A + (size_t)m0 * K);
  const char* Bg = (const char*)(B + (size_t)n0 * K);

#define STAGE_U(dst, src, ks)                                                   \
  { _Pragma("unroll")                                                           \
    for (int p = 0; p < 2; ++p) {                                               \
      int c = p * 256 + t;                                                      \
      int row = c >> 2;                                                         \
      int c16 = (c & 3) ^ ((row >> 1) & 3);                                     \
      __builtin_amdgcn_global_load_lds(                                         \
        (const __attribute__((address_space(1))) void*)                         \
          ((src) + (size_t)row * (size_t)(K * 2) + (size_t)(ks) * 64 + c16 * 16), \
        (__attribute__((address_space(3))) void*)((dst) + c * 16), 16, 0, 0);   \
    } }

  f32x4 acc[4][4] = {};
  bf16x8 a[4], b[4];
  char* const s0 = smem;
  char* const s1 = smem + 16384;

#define RD_B(base)                                                              \
  { _Pragma("unroll")                                                           \
    for (int j = 0; j < 4; ++j) {                                               \
      int row = wn * 64 + j * 16 + lr;                                          \
      b[j] = *reinterpret_cast<const bf16x8*>(                                  \
          (base) + 8192 + row * 64 + ((lh ^ ((row >> 1) & 3)) << 4));           \
    } }
#define RD_A2(base, i0)                                                         \
  { _Pragma("unroll")                                                           \
    for (int ii = 0; ii < 2; ++ii) {                                            \
      int row = wm * 64 + ((i0) + ii) * 16 + lr;                                \
      a[(i0) + ii] = *reinterpret_cast<const bf16x8*>(                          \
          (base) + row * 64 + ((lh ^ ((row >> 1) & 3)) << 4));                  \
    } }
#define MFMA8(i0)                                                               \
  asm volatile("s_waitcnt lgkmcnt(0)" ::: "memory");                            \
  __builtin_amdgcn_sched_barrier(0);                                            \
  __builtin_amdgcn_s_setprio(1);                                                \
  { _Pragma("unroll")                                                           \
    for (int ii = 0; ii < 2; ++ii)                                              \
      _Pragma("unroll")                                                         \
      for (int j = 0; j < 4; ++j)                                               \
        acc[(i0) + ii][j] =                                                     \
          __builtin_amdgcn_mfma_f32_16x16x32_bf16(a[(i0)+ii], b[j], acc[(i0)+ii][j], 0, 0, 0); } \
  __builtin_amdgcn_s_setprio(0);                                                \
  __builtin_amdgcn_sched_barrier(0);
#define BAR  __builtin_amdgcn_s_barrier(); __builtin_amdgcn_sched_barrier(0);

  const int NK = K >> 5;
  STAGE_U(s0, Ag, 0);
  STAGE_U(s0 + 8192, Bg, 0);

  for (int it2 = 0; it2 < (NK >> 1); ++it2) {
    const int k1 = 2 * it2 + 1, k2 = 2 * it2 + 2;
    STAGE_U(s1, Ag, k1);
    asm volatile("s_waitcnt vmcnt(2)" ::: "memory");
    BAR;
    RD_B(s0); RD_A2(s0, 0);
    MFMA8(0);
    BAR;
    RD_A2(s0, 2);
    STAGE_U(s1 + 8192, Bg, k1);
    MFMA8(2);
    BAR;
    if (k2 < NK) {
      STAGE_U(s0, Ag, k2);
      asm volatile("s_waitcnt vmcnt(2)" ::: "memory");
    } else {
      asm volatile("s_waitcnt vmcnt(0)" ::: "memory");
    }
    BAR;
    RD_B(s1); RD_A2(s1, 0);
    MFMA8(0);
    BAR;
    RD_A2(s1, 2);
    if (k2 < NK) STAGE_U(s0 + 8192, Bg, k2);
    MFMA8(2);
    BAR;
  }
#undef STAGE_U
#undef RD_A2
#undef RD_B
#undef MFMA8
#undef BAR

  #pragma unroll
  for (int j = 0; j < 4; ++j) {
    const int col = n0 + wn * 64 + j * 16 + lr;
    float bv;
    if constexpr (MODE == 0) bv = bias0[col];
    else bv = (col < 2048) ? bias0[col] : bias1[col - 2048];
    #pragma unroll
    for (int i = 0; i < 4; ++i) {
      #pragma unroll
      for (int r = 0; r < 4; ++r) {
        const int row = m0 + wm * 64 + i * 16 + lh * 4 + r;
        float v = acc[i][j][r] + bv;
        if constexpr (MODE == 0) {
          reinterpret_cast<float*>(out0)[(size_t)row * N + col] = v;
        } else {
          float qv = (col < 2048) ? v * 0.1275187541f : v;
          reinterpret_cast<bf16_t*>(out0)[(size_t)row * N + col] = (bf16_t)qv;
          if (col >= 2048) {
            const int local = col - 2048;
            const int which = local >> 9;
            const int hd    = local & 511;
            kvout[(size_t)which * 2097152 +
                  ((size_t)(hd >> 7) * 4096 + row) * 128 + (hd & 127)] = v;
            if (local >= 512) {
              const int c2 = local - 512;
              vt[(size_t)(c2 >> 7) * 524288 + (size_t)(c2 & 127) * 4096 + row] = (bf16_t)v;
            }
          }
        }
      }
    }
  }
}

// ---------------- causal GQA flash attention ----------------
// r11 iteration body, occupancy raised 2->3 blocks/CU (issue-bound kernel:
// VALU 46% + MFMA 27% at 2 waves/SIMD -> add TLP). Changes vs r11:
//  - V single-buffered (staged for it+1 after the bottom barrier; one full
//    iteration covers the DMA) -> LDS 48KB -> 3 blocks/CU.
//  - grid (64,16) = 1024 blocks (>= 3x256), ONE 64-row tile per block,
//    largest-first (xt = 63-x) for greedy balance of the 1..64-iter jobs.
//  - vmcnt: steady gate vmcnt(4) (only K(it+1) in flight), tail vmcnt(0).
// Waves: g = w>>1 key-half, wq = w&1 q-sub (32 rows, 2 subtiles of 16).
// Fixed-max softmax, in-register P, ones-MFMA row sums, key-half LDS merge.
__global__ __launch_bounds__(256, 3)
void attn_kernel(const bf16_t* __restrict__ QKVb, const bf16_t* __restrict__ Vt,
                 bf16_t* __restrict__ Ob) {
  __shared__ __align__(16) char smem[49152];   // [0,32K): K x2 ; [32K,48K): V
  const int t = threadIdx.x;
  const int w = t >> 6, l = t & 63;
  const int lr = l & 15, lh = l >> 4;
  const int g = w >> 1;                        // key-half group
  const int wq = w & 1;                        // q-sub owner (32 rows)
  const int h = blockIdx.y, kvh = h >> 2;

  const char* Kg = (const char*)(QKVb + 2048 + (size_t)kvh * 128);  // row 6144 B
  const char* Vg = (const char*)(Vt + (size_t)kvh * 524288);        // row 8192 B

// 256 threads: 4 chunks of 16B per thread per 16KB tile
#define STAGE_K(buf, kv0)                                                          \
  {                                                                                \
    _Pragma("unroll")                                                              \
    for (int p = 0; p < 4; ++p) {                                                  \
      int chunk = p * 256 + t;                                                     \
      int row = chunk >> 4, cb = (chunk & 15) << 4;                                \
      __builtin_amdgcn_global_load_lds(                                            \
        (const __attribute__((address_space(1))) void*)                            \
            (Kg + (size_t)((kv0) + row) * 6144 + (cb ^ ((row & 7) << 4))),         \
        (__attribute__((address_space(3))) void*)(smem + (buf) * 16384 + chunk * 16),\
        16, 0, 0);                                                                 \
    }                                                                              \
  }
#define STAGE_V(kv0)                                                               \
  {                                                                                \
    _Pragma("unroll")                                                              \
    for (int p = 0; p < 4; ++p) {                                                  \
      int chunk = p * 256 + t;                                                     \
      int row = chunk >> 3, cb = (chunk & 7) << 4;                                 \
      __builtin_amdgcn_global_load_lds(                                            \
        (const __attribute__((address_space(1))) void*)                            \
            (Vg + (size_t)row * 8192 + (size_t)(kv0) * 2 + (cb ^ ((row & 7) << 4))),\
        (__attribute__((address_space(3))) void*)(smem + 32768 + chunk * 16),      \
        16, 0, 0);                                                                 \
    }                                                                              \
  }

  bf16x8 onesf;
  #pragma unroll
  for (int j = 0; j < 8; ++j) onesf[j] = (bf16_t)1.0f;

  const int xt = 63 - (int)blockIdx.x;         // largest tiles dispatched first
  const int q0w = xt * 64 + wq * 32;
  const int nIter = xt + 1;

  bf16x8 qf[2][4];
  #pragma unroll
  for (int sub = 0; sub < 2; ++sub) {
    const bf16_t* qp = QKVb + (size_t)(q0w + sub * 16 + lr) * LDQ + h * 128 + lh * 8;
    #pragma unroll
    for (int kc = 0; kc < 4; ++kc) qf[sub][kc] = *reinterpret_cast<const bf16x8*>(qp + kc * 32);
  }
  __builtin_amdgcn_sched_barrier(0);
  STAGE_K(0, 0);                               // 4 loads
  __builtin_amdgcn_sched_barrier(0);
  STAGE_V(0);                                  // 4 loads
  __builtin_amdgcn_sched_barrier(0);
  if (nIter > 1) STAGE_K(1, 64);               // 4 loads
  __builtin_amdgcn_sched_barrier(0);

  f32x4 oacc[2][8] = {};
  f32x4 lacc[2] = {};

  auto body = [&](int it, bool masked) {
    const int cur = it & 1;
    const int kv0 = it * 64;
    // K(it)+V(it) resident; only K(it+1) (4 loads) may stay in flight
    if (it + 1 < nIter) { asm volatile("s_waitcnt vmcnt(4)" ::: "memory"); }
    else                { asm volatile("s_waitcnt vmcnt(0)" ::: "memory"); }
    __builtin_amdgcn_s_barrier();
    __builtin_amdgcn_sched_barrier(0);

    // ---- S^T = K Q^T on this group's 32 keys ----
    const char* kb = smem + cur * 16384;
    f32x4 s[2][2] = {};    // [sub][n2]
    __builtin_amdgcn_s_setprio(1);
    #pragma unroll
    for (int n2 = 0; n2 < 2; ++n2) {
      const int row = g * 32 + n2 * 16 + lr;
      const int sw = (row & 7) << 4;
      #pragma unroll
      for (int kc = 0; kc < 4; ++kc) {
        bf16x8 kf = *reinterpret_cast<const bf16x8*>(kb + row * 256 + ((kc * 64 + lh * 16) ^ sw));
        s[0][n2] = __builtin_amdgcn_mfma_f32_16x16x32_bf16(kf, qf[0][kc], s[0][n2], 0, 0, 0);
        s[1][n2] = __builtin_amdgcn_mfma_f32_16x16x32_bf16(kf, qf[1][kc], s[1][n2], 0, 0, 0);
      }
    }
    __builtin_amdgcn_s_setprio(0);

    // ---- P = exp2(S) in registers; PV A-frag elems [n2*4+r] <- key n2*16+lh*4+r ----
    bf16x8 pa[2];
    #pragma unroll
    for (int sub = 0; sub < 2; ++sub) {
      const int qs = q0w + sub * 16;
      const bool needM = masked && (kv0 + g * 32 + 31 > qs);
      bf16x8 v;
      #pragma unroll
      for (int n2 = 0; n2 < 2; ++n2) {
        #pragma unroll
        for (int r = 0; r < 4; ++r) {
          float p = exp2f(s[sub][n2][r]);
          if (needM && (kv0 + g * 32 + n2 * 16 + lh * 4 + r > qs + lr)) p = 0.f;
          v[n2 * 4 + r] = (bf16_t)p;
        }
      }
      pa[sub] = v;
    }
    lacc[0] = __builtin_amdgcn_mfma_f32_16x16x32_bf16(pa[0], onesf, lacc[0], 0, 0, 0);
    lacc[1] = __builtin_amdgcn_mfma_f32_16x16x32_bf16(pa[1], onesf, lacc[1], 0, 0, 0);

    // ---- O += P V over this key-half (V single buffer) ----
    const char* vb0 = smem + 32768;
    __builtin_amdgcn_s_setprio(1);
    #pragma unroll
    for (int nb = 0; nb < 8; ++nb) {
      const int row = nb * 16 + lr;
      const int sw2 = (row & 7) << 4;
      const char* vb = vb0 + row * 128;
      bf16x4 lo = *reinterpret_cast<const bf16x4*>(vb + ((g * 64 + lh * 8) ^ sw2));
      bf16x4 hi = *reinterpret_cast<const bf16x4*>(vb + ((g * 64 + 32 + lh * 8) ^ sw2));
      bf16x8 vf = __builtin_shufflevector(lo, hi, 0, 1, 2, 3, 4, 5, 6, 7);
      oacc[0][nb] = __builtin_amdgcn_mfma_f32_16x16x32_bf16(pa[0], vf, oacc[0][nb], 0, 0, 0);
      oacc[1][nb] = __builtin_amdgcn_mfma_f32_16x16x32_bf16(pa[1], vf, oacc[1][nb], 0, 0, 0);
    }
    __builtin_amdgcn_s_setprio(0);

    // ---- all waves done with V(it) and K slot cur -> refill ----
    __builtin_amdgcn_sched_barrier(0);
    __builtin_amdgcn_s_barrier();
    __builtin_amdgcn_sched_barrier(0);
    if (it + 1 < nIter) STAGE_V(kv0 + 64);               // 4 loads (first)
    __builtin_amdgcn_sched_barrier(0);
    if (it + 2 < nIter) STAGE_K(cur, kv0 + 128);         // 4 loads (second)
    __builtin_amdgcn_sched_barrier(0);
  };

  for (int it = 0; it < nIter - 1; ++it) body(it, false);   // unmasked main loop
  body(nIter - 1, true);                                    // diagonal tile

  // ---- merge key-half partials through (now-dead) LDS ----
  bf16_t* mO = (bf16_t*)smem;              // [2][32][128] bf16 = 16KB
  float*  mL = (float*)(smem + 16384);     // [2][32] f32
  if (g == 1) {
    #pragma unroll
    for (int sub = 0; sub < 2; ++sub) {
      #pragma unroll
      for (int nb = 0; nb < 8; ++nb)
        #pragma unroll
        for (int r = 0; r < 4; ++r)
          mO[((wq * 32 + sub * 16 + lh * 4 + r) << 7) + nb * 16 + lr] = (bf16_t)oacc[sub][nb][r];
      if (lr == 0)
        #pragma unroll
        for (int r = 0; r < 4; ++r) mL[wq * 32 + sub * 16 + lh * 4 + r] = lacc[sub][r];
    }
  }
  __syncthreads();
  if (g == 0) {
    #pragma unroll
    for (int sub = 0; sub < 2; ++sub) {
      f32x4 linv;
      #pragma unroll
      for (int r = 0; r < 4; ++r)
        linv[r] = 1.0f / (lacc[sub][r] + mL[wq * 32 + sub * 16 + lh * 4 + r]);
      #pragma unroll
      for (int nb = 0; nb < 8; ++nb) {
        #pragma unroll
        for (int r = 0; r < 4; ++r) {
          float o1 = (float)mO[((wq * 32 + sub * 16 + lh * 4 + r) << 7) + nb * 16 + lr];
          float v = (oacc[sub][nb][r] + o1) * linv[r];
          Ob[(size_t)(q0w + sub * 16 + lh * 4 + r) * 2048 + h * 128 + nb * 16 + lr] = (bf16_t)v;
        }
      }
    }
  }
#undef STAGE_K
#undef STAGE_V
}

extern "C" void kernel_launch(void* const* d_in, const int* in_sizes, int n_in,
                              void* d_out, int out_size, void* d_ws, size_t ws_size,
                              hipStream_t stream) {
  const float* seq   = (const float*)d_in[0];
  const float* Wq_w  = (const float*)d_in[2];
  const float* Wq_b  = (const float*)d_in[3];
  const float* Wkv_w = (const float*)d_in[4];
  const float* Wkv_b = (const float*)d_in[5];
  const float* Wo_w  = (const float*)d_in[6];
  const float* Wo_b  = (const float*)d_in[7];

  float* out   = (float*)d_out;
  float* kvout = out + (size_t)4096 * 2048;

  char* ws = (char*)d_ws;
  bf16_t* seqb = (bf16_t*)ws;                          // [4096][2048] (reused as Ob)
  bf16_t* wqkv = (bf16_t*)(ws + 16777216);             // [3072][2048]
  bf16_t* wob  = (bf16_t*)(ws + 29360128);             // [2048][2048]
  bf16_t* qkvb = (bf16_t*)(ws + 37748736);             // [4096][3072]
  bf16_t* vt   = (bf16_t*)(ws + 62914560);             // [4][128][4096]
  bf16_t* ob   = seqb;

  cast4_kernel<<<9216, 256, 0, stream>>>(seq, seqb, Wq_w, wqkv,
                                         Wkv_w, wqkv + 4194304, Wo_w, wob);

  gemm128<1><<<dim3(32, 24), 256, 0, stream>>>(seqb, wqkv, Wq_b, Wkv_b,
                                               qkvb, kvout, vt, 4096, 3072, 2048);
  attn_kernel<<<dim3(64, 16), 256, 0, stream>>>(qkvb, vt, ob);
  gemm128<0><<<dim3(32, 16), 256, 0, stream>>>(ob, wob, Wo_b, nullptr,
                                               out, nullptr, nullptr, 4096, 2048, 2048);
}

// Round 17
// 219.977 us; speedup vs baseline: 1.2090x; 1.2090x over previous
//
#include <hip/hip_runtime.h>
#include <cstdint>
#include <cstddef>

typedef __bf16 bf16_t;
typedef __bf16 bf16x4 __attribute__((ext_vector_type(4)));
typedef __bf16 bf16x8 __attribute__((ext_vector_type(8)));
typedef float  f32x4  __attribute__((ext_vector_type(4)));

#define LDQ 3072   // QKV buffer row stride (elements)

// ---------------- fused cast f32 -> bf16: 4 regions, one launch ----------------
__global__ __launch_bounds__(256)
void cast4_kernel(const float* __restrict__ s0, bf16_t* __restrict__ d0,  // seq   1048576
                  const float* __restrict__ s1, bf16_t* __restrict__ d1,  // Wq    524288
                  const float* __restrict__ s2, bf16_t* __restrict__ d2,  // Wkv   262144
                  const float* __restrict__ s3, bf16_t* __restrict__ d3)  // Wo    524288
{
  int i = blockIdx.x * 256 + threadIdx.x;     // 8-elem unit index, total 2359296
  const float* src; bf16_t* dst; int off;
  if (i < 1048576)      { src = s0; dst = d0; off = i; }
  else if (i < 1572864) { src = s1; dst = d1; off = i - 1048576; }
  else if (i < 1835008) { src = s2; dst = d2; off = i - 1572864; }
  else                  { src = s3; dst = d3; off = i - 1835008; }
  const float4* p = reinterpret_cast<const float4*>(src) + (size_t)off * 2;
  float4 a = p[0], b = p[1];
  bf16x8 o;
  o[0] = (bf16_t)a.x; o[1] = (bf16_t)a.y; o[2] = (bf16_t)a.z; o[3] = (bf16_t)a.w;
  o[4] = (bf16_t)b.x; o[5] = (bf16_t)b.y; o[6] = (bf16_t)b.z; o[7] = (bf16_t)b.w;
  *reinterpret_cast<bf16x8*>(dst + (size_t)off * 8) = o;
}

// ---------------- GEMM 128x128, BK=32, 4-phase counted-vmcnt (r11) ----------
template <int MODE>
__global__ __launch_bounds__(256, 3)
void gemm128(const bf16_t* __restrict__ A, const bf16_t* __restrict__ B,
             const float* __restrict__ bias0, const float* __restrict__ bias1,
             void* __restrict__ out0, float* __restrict__ kvout,
             bf16_t* __restrict__ vt, int M, int N, int K) {
  __shared__ __align__(16) char smem[32768];
  const int t = threadIdx.x;
  const int l = t & 63;
  const int lr = l & 15, lh = l >> 4;
  const int w = t >> 6;
  const int wm = w >> 1, wn = w & 1;
  const int m0 = blockIdx.x * 128, n0 = blockIdx.y * 128;

  const char* Ag = (const char*)(A + (size_t)m0 * K);
  const char* Bg = (const char*)(B + (size_t)n0 * K);

#define STAGE_U(dst, src, ks)                                                   \
  { _Pragma("unroll")                                                           \
    for (int p = 0; p < 2; ++p) {                                               \
      int c = p * 256 + t;                                                      \
      int row = c >> 2;                                                         \
      int c16 = (c & 3) ^ ((row >> 1) & 3);                                     \
      __builtin_amdgcn_global_load_lds(                                         \
        (const __attribute__((address_space(1))) void*)                         \
          ((src) + (size_t)row * (size_t)(K * 2) + (size_t)(ks) * 64 + c16 * 16), \
        (__attribute__((address_space(3))) void*)((dst) + c * 16), 16, 0, 0);   \
    } }

  f32x4 acc[4][4] = {};
  bf16x8 a[4], b[4];
  char* const s0 = smem;
  char* const s1 = smem + 16384;

#define RD_B(base)                                                              \
  { _Pragma("unroll")                                                           \
    for (int j = 0; j < 4; ++j) {                                               \
      int row = wn * 64 + j * 16 + lr;                                          \
      b[j] = *reinterpret_cast<const bf16x8*>(                                  \
          (base) + 8192 + row * 64 + ((lh ^ ((row >> 1) & 3)) << 4));           \
    } }
#define RD_A2(base, i0)                                                         \
  { _Pragma("unroll")                                                           \
    for (int ii = 0; ii < 2; ++ii) {                                            \
      int row = wm * 64 + ((i0) + ii) * 16 + lr;                                \
      a[(i0) + ii] = *reinterpret_cast<const bf16x8*>(                          \
          (base) + row * 64 + ((lh ^ ((row >> 1) & 3)) << 4));                  \
    } }
#define MFMA8(i0)                                                               \
  asm volatile("s_waitcnt lgkmcnt(0)" ::: "memory");                            \
  __builtin_amdgcn_sched_barrier(0);                                            \
  __builtin_amdgcn_s_setprio(1);                                                \
  { _Pragma("unroll")                                                           \
    for (int ii = 0; ii < 2; ++ii)                                              \
      _Pragma("unroll")                                                         \
      for (int j = 0; j < 4; ++j)                                               \
        acc[(i0) + ii][j] =                                                     \
          __builtin_amdgcn_mfma_f32_16x16x32_bf16(a[(i0)+ii], b[j], acc[(i0)+ii][j], 0, 0, 0); } \
  __builtin_amdgcn_s_setprio(0);                                                \
  __builtin_amdgcn_sched_barrier(0);
#define BAR  __builtin_amdgcn_s_barrier(); __builtin_amdgcn_sched_barrier(0);

  const int NK = K >> 5;
  STAGE_U(s0, Ag, 0);
  STAGE_U(s0 + 8192, Bg, 0);

  for (int it2 = 0; it2 < (NK >> 1); ++it2) {
    const int k1 = 2 * it2 + 1, k2 = 2 * it2 + 2;
    STAGE_U(s1, Ag, k1);
    asm volatile("s_waitcnt vmcnt(2)" ::: "memory");
    BAR;
    RD_B(s0); RD_A2(s0, 0);
    MFMA8(0);
    BAR;
    RD_A2(s0, 2);
    STAGE_U(s1 + 8192, Bg, k1);
    MFMA8(2);
    BAR;
    if (k2 < NK) {
      STAGE_U(s0, Ag, k2);
      asm volatile("s_waitcnt vmcnt(2)" ::: "memory");
    } else {
      asm volatile("s_waitcnt vmcnt(0)" ::: "memory");
    }
    BAR;
    RD_B(s1); RD_A2(s1, 0);
    MFMA8(0);
    BAR;
    RD_A2(s1, 2);
    if (k2 < NK) STAGE_U(s0 + 8192, Bg, k2);
    MFMA8(2);
    BAR;
  }
#undef STAGE_U
#undef RD_A2
#undef RD_B
#undef MFMA8
#undef BAR

  #pragma unroll
  for (int j = 0; j < 4; ++j) {
    const int col = n0 + wn * 64 + j * 16 + lr;
    float bv;
    if constexpr (MODE == 0) bv = bias0[col];
    else bv = (col < 2048) ? bias0[col] : bias1[col - 2048];
    #pragma unroll
    for (int i = 0; i < 4; ++i) {
      #pragma unroll
      for (int r = 0; r < 4; ++r) {
        const int row = m0 + wm * 64 + i * 16 + lh * 4 + r;
        float v = acc[i][j][r] + bv;
        if constexpr (MODE == 0) {
          reinterpret_cast<float*>(out0)[(size_t)row * N + col] = v;
        } else {
          float qv = (col < 2048) ? v * 0.1275187541f : v;
          reinterpret_cast<bf16_t*>(out0)[(size_t)row * N + col] = (bf16_t)qv;
          if (col >= 2048) {
            const int local = col - 2048;
            const int which = local >> 9;
            const int hd    = local & 511;
            kvout[(size_t)which * 2097152 +
                  ((size_t)(hd >> 7) * 4096 + row) * 128 + (hd & 127)] = v;
            if (local >= 512) {
              const int c2 = local - 512;
              vt[(size_t)(c2 >> 7) * 524288 + (size_t)(c2 & 127) * 4096 + row] = (bf16_t)v;
            }
          }
        }
      }
    }
  }
}

// ---------------- causal GQA flash attention (r15/r11, best measured) ----------
// grid (32, 16) = 512 blocks (exactly 2/CU), 256 thr = 4 waves.
// Block processes 64-row q-tile pair {x, 63-x}: exactly 65 KV-iters/block.
// Waves: g = w>>1 key-half, wq = w&1 q-sub (32 rows, 2 subtiles of 16).
// Fixed-max softmax, in-register P, ones-MFMA row sums, key-half LDS merge.
__global__ __launch_bounds__(256, 2)
void attn_kernel(const bf16_t* __restrict__ QKVb, const bf16_t* __restrict__ Vt,
                 bf16_t* __restrict__ Ob) {
  __shared__ __align__(16) char smem[65536];   // [0,32K): K x2 ; [32K,64K): V x2
  const int t = threadIdx.x;
  const int w = t >> 6, l = t & 63;
  const int lr = l & 15, lh = l >> 4;
  const int g = w >> 1;                        // key-half group
  const int wq = w & 1;                        // q-sub owner (32 rows)
  const int h = blockIdx.y, kvh = h >> 2;

  const char* Kg = (const char*)(QKVb + 2048 + (size_t)kvh * 128);  // row 6144 B
  const char* Vg = (const char*)(Vt + (size_t)kvh * 524288);        // row 8192 B

// 256 threads: 4 chunks of 16B per thread per 16KB tile
#define STAGE_K(buf, kv0)                                                          \
  {                                                                                \
    _Pragma("unroll")                                                              \
    for (int p = 0; p < 4; ++p) {                                                  \
      int chunk = p * 256 + t;                                                     \
      int row = chunk >> 4, cb = (chunk & 15) << 4;                                \
      __builtin_amdgcn_global_load_lds(                                            \
        (const __attribute__((address_space(1))) void*)                            \
            (Kg + (size_t)((kv0) + row) * 6144 + (cb ^ ((row & 7) << 4))),         \
        (__attribute__((address_space(3))) void*)(smem + (buf) * 16384 + chunk * 16),\
        16, 0, 0);                                                                 \
    }                                                                              \
  }
#define STAGE_V(buf, kv0)                                                          \
  {                                                                                \
    _Pragma("unroll")                                                              \
    for (int p = 0; p < 4; ++p) {                                                  \
      int chunk = p * 256 + t;                                                     \
      int row = chunk >> 3, cb = (chunk & 7) << 4;                                 \
      __builtin_amdgcn_global_load_lds(                                            \
        (const __attribute__((address_space(1))) void*)                            \
            (Vg + (size_t)row * 8192 + (size_t)(kv0) * 2 + (cb ^ ((row & 7) << 4))),\
        (__attribute__((address_space(3))) void*)(smem + 32768 + (buf) * 16384 + chunk * 16),\
        16, 0, 0);                                                                 \
    }                                                                              \
  }

  bf16x8 onesf;
  #pragma unroll
  for (int j = 0; j < 8; ++j) onesf[j] = (bf16_t)1.0f;

  for (int ph = 0; ph < 2; ++ph) {
    const int xt = ph ? 63 - (int)blockIdx.x : (int)blockIdx.x;   // pair {x, 63-x}
    const int q0b = xt * 64;
    const int q0w = q0b + wq * 32;
    const int nIter = xt + 1;

    bf16x8 qf[2][4];
    #pragma unroll
    for (int sub = 0; sub < 2; ++sub) {
      const bf16_t* qp = QKVb + (size_t)(q0w + sub * 16 + lr) * LDQ + h * 128 + lh * 8;
      #pragma unroll
      for (int kc = 0; kc < 4; ++kc) qf[sub][kc] = *reinterpret_cast<const bf16x8*>(qp + kc * 32);
    }
    __builtin_amdgcn_sched_barrier(0);
    STAGE_K(0, 0);
    STAGE_V(0, 0);
    __builtin_amdgcn_sched_barrier(0);
    STAGE_K(1, 64);     // keys 64..127 always exist (S=4096); unused if nIter==1
    STAGE_V(1, 64);
    __builtin_amdgcn_sched_barrier(0);

    f32x4 oacc[2][8] = {};
    f32x4 lacc[2] = {};

    auto body = [&](int it, bool masked) {
      const int cur = it & 1;
      const int kv0 = it * 64;
      // tile it resident; tile it+1 (8 loads/thread) may stay in flight (T4)
      if (it + 1 < nIter) { asm volatile("s_waitcnt vmcnt(8)" ::: "memory"); }
      else                { asm volatile("s_waitcnt vmcnt(0)" ::: "memory"); }
      __builtin_amdgcn_s_barrier();
      __builtin_amdgcn_sched_barrier(0);

      // ---- S^T = K Q^T on this group's 32 keys ----
      const char* kb = smem + cur * 16384;
      f32x4 s[2][2] = {};    // [sub][n2]
      __builtin_amdgcn_s_setprio(1);
      #pragma unroll
      for (int n2 = 0; n2 < 2; ++n2) {
        const int row = g * 32 + n2 * 16 + lr;
        const int sw = (row & 7) << 4;
        #pragma unroll
        for (int kc = 0; kc < 4; ++kc) {
          bf16x8 kf = *reinterpret_cast<const bf16x8*>(kb + row * 256 + ((kc * 64 + lh * 16) ^ sw));
          s[0][n2] = __builtin_amdgcn_mfma_f32_16x16x32_bf16(kf, qf[0][kc], s[0][n2], 0, 0, 0);
          s[1][n2] = __builtin_amdgcn_mfma_f32_16x16x32_bf16(kf, qf[1][kc], s[1][n2], 0, 0, 0);
        }
      }
      __builtin_amdgcn_s_setprio(0);

      // ---- P = exp2(S) in registers; PV A-frag elems [n2*4+r] <- key n2*16+lh*4+r ----
      bf16x8 pa[2];
      #pragma unroll
      for (int sub = 0; sub < 2; ++sub) {
        const int qs = q0w + sub * 16;
        const bool needM = masked && (kv0 + g * 32 + 31 > qs);
        bf16x8 v;
        #pragma unroll
        for (int n2 = 0; n2 < 2; ++n2) {
          #pragma unroll
          for (int r = 0; r < 4; ++r) {
            float p = exp2f(s[sub][n2][r]);
            if (needM && (kv0 + g * 32 + n2 * 16 + lh * 4 + r > qs + lr)) p = 0.f;
            v[n2 * 4 + r] = (bf16_t)p;
          }
        }
        pa[sub] = v;
      }
      lacc[0] = __builtin_amdgcn_mfma_f32_16x16x32_bf16(pa[0], onesf, lacc[0], 0, 0, 0);
      lacc[1] = __builtin_amdgcn_mfma_f32_16x16x32_bf16(pa[1], onesf, lacc[1], 0, 0, 0);

      // ---- O += P V over this key-half ----
      const char* vb0 = smem + 32768 + cur * 16384;
      __builtin_amdgcn_s_setprio(1);
      #pragma unroll
      for (int nb = 0; nb < 8; ++nb) {
        const int row = nb * 16 + lr;
        const int sw2 = (row & 7) << 4;
        const char* vb = vb0 + row * 128;
        bf16x4 lo = *reinterpret_cast<const bf16x4*>(vb + ((g * 64 + lh * 8) ^ sw2));
        bf16x4 hi = *reinterpret_cast<const bf16x4*>(vb + ((g * 64 + 32 + lh * 8) ^ sw2));
        bf16x8 vf = __builtin_shufflevector(lo, hi, 0, 1, 2, 3, 4, 5, 6, 7);
        oacc[0][nb] = __builtin_amdgcn_mfma_f32_16x16x32_bf16(pa[0], vf, oacc[0][nb], 0, 0, 0);
        oacc[1][nb] = __builtin_amdgcn_mfma_f32_16x16x32_bf16(pa[1], vf, oacc[1][nb], 0, 0, 0);
      }
      __builtin_amdgcn_s_setprio(0);

      __builtin_amdgcn_sched_barrier(0);
      __builtin_amdgcn_s_barrier();
      __builtin_amdgcn_sched_barrier(0);
      if (it + 2 < nIter) { STAGE_K(cur, kv0 + 128); STAGE_V(cur, kv0 + 128); }
    };

    for (int it = 0; it < nIter - 1; ++it) body(it, false);   // unmasked main loop
    body(nIter - 1, true);                                    // diagonal tile

    // ---- merge key-half partials through (now-dead) LDS ----
    bf16_t* mO = (bf16_t*)smem;              // [2][32][128] bf16 = 16KB
    float*  mL = (float*)(smem + 32768);     // [2][32] f32
    if (g == 1) {
      #pragma unroll
      for (int sub = 0; sub < 2; ++sub) {
        #pragma unroll
        for (int nb = 0; nb < 8; ++nb)
          #pragma unroll
          for (int r = 0; r < 4; ++r)
            mO[((wq * 32 + sub * 16 + lh * 4 + r) << 7) + nb * 16 + lr] = (bf16_t)oacc[sub][nb][r];
        if (lr == 0)
          #pragma unroll
          for (int r = 0; r < 4; ++r) mL[wq * 32 + sub * 16 + lh * 4 + r] = lacc[sub][r];
      }
    }
    __syncthreads();
    if (g == 0) {
      #pragma unroll
      for (int sub = 0; sub < 2; ++sub) {
        f32x4 linv;
        #pragma unroll
        for (int r = 0; r < 4; ++r)
          linv[r] = 1.0f / (lacc[sub][r] + mL[wq * 32 + sub * 16 + lh * 4 + r]);
        #pragma unroll
        for (int nb = 0; nb < 8; ++nb) {
          #pragma unroll
          for (int r = 0; r < 4; ++r) {
            float o1 = (float)mO[((wq * 32 + sub * 16 + lh * 4 + r) << 7) + nb * 16 + lr];
            float v = (oacc[sub][nb][r] + o1) * linv[r];
            Ob[(size_t)(q0w + sub * 16 + lh * 4 + r) * 2048 + h * 128 + nb * 16 + lr] = (bf16_t)v;
          }
        }
      }
    }
    __syncthreads();   // protect merge region from next phase's staging
  }
#undef STAGE_K
#undef STAGE_V
}

extern "C" void kernel_launch(void* const* d_in, const int* in_sizes, int n_in,
                              void* d_out, int out_size, void* d_ws, size_t ws_size,
                              hipStream_t stream) {
  const float* seq   = (const float*)d_in[0];
  const float* Wq_w  = (const float*)d_in[2];
  const float* Wq_b  = (const float*)d_in[3];
  const float* Wkv_w = (const float*)d_in[4];
  const float* Wkv_b = (const float*)d_in[5];
  const float* Wo_w  = (const float*)d_in[6];
  const float* Wo_b  = (const float*)d_in[7];

  float* out   = (float*)d_out;
  float* kvout = out + (size_t)4096 * 2048;

  char* ws = (char*)d_ws;
  bf16_t* seqb = (bf16_t*)ws;                          // [4096][2048] (reused as Ob)
  bf16_t* wqkv = (bf16_t*)(ws + 16777216);             // [3072][2048]
  bf16_t* wob  = (bf16_t*)(ws + 29360128);             // [2048][2048]
  bf16_t* qkvb = (bf16_t*)(ws + 37748736);             // [4096][3072]
  bf16_t* vt   = (bf16_t*)(ws + 62914560);             // [4][128][4096]
  bf16_t* ob   = seqb;

  cast4_kernel<<<9216, 256, 0, stream>>>(seq, seqb, Wq_w, wqkv,
                                         Wkv_w, wqkv + 4194304, Wo_w, wob);

  gemm128<1><<<dim3(32, 24), 256, 0, stream>>>(seqb, wqkv, Wq_b, Wkv_b,
                                               qkvb, kvout, vt, 4096, 3072, 2048);
  attn_kernel<<<dim3(32, 16), 256, 0, stream>>>(qkvb, vt, ob);
  gemm128<0><<<dim3(32, 16), 256, 0, stream>>>(ob, wob, Wo_b, nullptr,
                                               out, nullptr, nullptr, 4096, 2048, 2048);
}